// Round 6
// baseline (1094.716 us; speedup 1.0000x reference)
//
#include <hip/hip_runtime.h>

static constexpr int FIN = 128;
static constexpr int HD  = 64;
static constexpr int CD  = 40;

// ---------------------------------------------------------------------------
// Matvec, output-split: thread = (node, o-group).  blockIdx.y picks a group
// of OG output rows; acc[OG] is small and statically indexed -> registers.
// Input row read from global (L2/L3-cached across y-blocks); weights at
// wave-uniform addresses -> s_load.  4-5x more blocks than one-thread-per-
// node => occupancy 16% -> 40%+ (R5 fix: latency-bound at 1.5 blocks/CU).
// ---------------------------------------------------------------------------
template<int K, int O, int OG, bool IN_RELU, bool OUT_RELU>
__global__ __launch_bounds__(256, 6)
void mv_kernel(const float* __restrict__ in, const float* __restrict__ W,
               const float* __restrict__ bias, float* __restrict__ out, int n)
{
    int node = blockIdx.x * 256 + threadIdx.x;
    if (node >= n) return;
    const int og0 = blockIdx.y * OG;
    float acc[OG];
#pragma unroll
    for (int oo = 0; oo < OG; ++oo) acc[oo] = bias[og0 + oo];
    const float* row = in + (size_t)node * K;
    const float* Wb  = W + (size_t)og0 * K;
#pragma unroll 1
    for (int k = 0; k < K; k += 4) {
        float4 v = *reinterpret_cast<const float4*>(row + k);
        if (IN_RELU) {
            v.x = fmaxf(v.x, 0.f); v.y = fmaxf(v.y, 0.f);
            v.z = fmaxf(v.z, 0.f); v.w = fmaxf(v.w, 0.f);
        }
#pragma unroll
        for (int oo = 0; oo < OG; ++oo) {
            const float* wr = Wb + oo * K + k;   // wave-uniform -> scalar load
            acc[oo] = fmaf(v.x, wr[0], acc[oo]);
            acc[oo] = fmaf(v.y, wr[1], acc[oo]);
            acc[oo] = fmaf(v.z, wr[2], acc[oo]);
            acc[oo] = fmaf(v.w, wr[3], acc[oo]);
        }
    }
    float* orow = out + (size_t)node * O + og0;
#pragma unroll
    for (int oo = 0; oo < OG; oo += 4) {
        float4 r;
        r.x = OUT_RELU ? fmaxf(acc[oo],     0.f) : acc[oo];
        r.y = OUT_RELU ? fmaxf(acc[oo + 1], 0.f) : acc[oo + 1];
        r.z = OUT_RELU ? fmaxf(acc[oo + 2], 0.f) : acc[oo + 2];
        r.w = OUT_RELU ? fmaxf(acc[oo + 3], 0.f) : acc[oo + 3];
        *reinterpret_cast<float4*>(orow + oo) = r;
    }
}

// ---------------------------------------------------------------------------
// CSR build.
// ---------------------------------------------------------------------------
__global__ __launch_bounds__(256)
void hist_kernel(const int* __restrict__ dst, int* __restrict__ deg, int e)
{
    int i = blockIdx.x * 256 + threadIdx.x;
    if (i < e) atomicAdd(&deg[dst[i]], 1);
}

__global__ __launch_bounds__(256)
void chunksum_kernel(const int* __restrict__ deg, int* __restrict__ chunkSum, int n)
{
    __shared__ int s[256];
    int t = threadIdx.x;
    int base = blockIdx.x * 1024 + t * 4;
    int v = 0;
#pragma unroll
    for (int i = 0; i < 4; ++i) if (base + i < n) v += deg[base + i];
    s[t] = v; __syncthreads();
    for (int off = 128; off > 0; off >>= 1) {
        if (t < off) s[t] += s[t + off];
        __syncthreads();
    }
    if (t == 0) chunkSum[blockIdx.x] = s[0];
}

__global__ __launch_bounds__(128)
void scanchunks_kernel(int* __restrict__ chunkSum, int nchunks)
{
    __shared__ int s[128];
    int t = threadIdx.x;
    int v = (t < nchunks) ? chunkSum[t] : 0;
    s[t] = v; __syncthreads();
    for (int off = 1; off < 128; off <<= 1) {
        int a = (t >= off) ? s[t - off] : 0;
        __syncthreads();
        s[t] += a;
        __syncthreads();
    }
    if (t < nchunks) chunkSum[t] = s[t] - v;   // exclusive
}

__global__ __launch_bounds__(256)
void scanwithin_kernel(const int* __restrict__ deg, const int* __restrict__ chunkOff,
                       int* __restrict__ rowptr, int n)
{
    __shared__ int s[256];
    int t = threadIdx.x;
    int base = blockIdx.x * 1024 + t * 4;
    int v[4]; int sum = 0;
#pragma unroll
    for (int i = 0; i < 4; ++i) { v[i] = (base + i < n) ? deg[base + i] : 0; sum += v[i]; }
    s[t] = sum; __syncthreads();
    for (int off = 1; off < 256; off <<= 1) {
        int a = (t >= off) ? s[t - off] : 0;
        __syncthreads();
        s[t] += a;
        __syncthreads();
    }
    int p = s[t] - sum + chunkOff[blockIdx.x];
#pragma unroll
    for (int i = 0; i < 4; ++i) {
        if (base + i < n) rowptr[base + i] = p;
        p += v[i];
    }
}

__global__ __launch_bounds__(256)
void fill_kernel(const int* __restrict__ src, const int* __restrict__ dst,
                 int* __restrict__ rowptr, int* __restrict__ eidx, int e)
{
    int i = blockIdx.x * 256 + threadIdx.x;
    if (i >= e) return;
    int pos = atomicAdd(&rowptr[dst[i]], 1);
    eidx[pos] = src[i];
}

// ---------------------------------------------------------------------------
// Gather: agg[d][c] = h[d][c] + sum_{e: dst=d} h[src_e][c].
// One wave per node, lane = channel.
// ---------------------------------------------------------------------------
template<int D>
__global__ __launch_bounds__(256)
void gather_kernel(const int* __restrict__ rowptr_end, const int* __restrict__ deg,
                   const int* __restrict__ eidx, const float* __restrict__ h,
                   float* __restrict__ agg, int n)
{
    int wave = threadIdx.x >> 6;
    int lane = threadIdx.x & 63;
    int node = blockIdx.x * 4 + wave;
    if (node >= n) return;
    bool act = (lane < D);
    float acc = act ? h[(size_t)node * D + lane] : 0.f;
    int end = rowptr_end[node];
    int start = end - deg[node];
    for (int base = start; base < end; base += 64) {
        int m = min(64, end - base);
        int sv = (lane < m) ? eidx[base + lane] : 0;
        for (int j = 0; j < m; ++j) {
            int s = __shfl(sv, j, 64);
            if (act) acc += h[(size_t)s * D + lane];
        }
    }
    if (act) agg[(size_t)node * D + lane] = acc;
}

extern "C" void kernel_launch(void* const* d_in, const int* in_sizes, int n_in,
                              void* d_out, int out_size, void* d_ws, size_t ws_size,
                              hipStream_t stream)
{
    const float* x      = (const float*)d_in[0];
    const int*   ei     = (const int*)d_in[1];
    const float* w1_lin = (const float*)d_in[2];
    const float* b1_lin = (const float*)d_in[3];
    const float* w1_o1  = (const float*)d_in[4];
    const float* b1_o1  = (const float*)d_in[5];
    const float* w1_o2  = (const float*)d_in[6];
    const float* b1_o2  = (const float*)d_in[7];
    const float* w2_lin = (const float*)d_in[8];
    const float* b2_lin = (const float*)d_in[9];
    const float* w2_o1  = (const float*)d_in[10];
    const float* b2_o1  = (const float*)d_in[11];
    const float* w2_o2  = (const float*)d_in[12];
    const float* b2_o2  = (const float*)d_in[13];

    const int n = in_sizes[0] / FIN;   // 100000
    const int e = in_sizes[1] / 2;     // 1000000
    const int* src = ei;
    const int* dst = ei + e;

    // Two float buffers in d_ws, strict ping-pong:
    float* ws0 = (float*)d_ws;
    float* ws1 = ws0 + (size_t)n * HD;
    float* outp = (float*)d_out;

    // CSR arrays live in d_out (16 MB; last consumer is gather40, before the
    // final mv writes d_out).
    int* eidx     = (int*)d_out;
    int* deg      = eidx + e;
    int* rowptr   = deg + n;
    int* chunkSum = rowptr + n;

    const int nchunks = (n + 1023) / 1024;        // 98 (<=128)
    const int egrid   = (e + 255) / 256;
    const int ngrid   = (n + 255) / 256;
    const int ggrid   = (n + 3) / 4;

    // ---- CSR build (reused by both layers) ----
    hipMemsetAsync(deg, 0, (size_t)n * sizeof(int), stream);
    hist_kernel<<<egrid, 256, 0, stream>>>(dst, deg, e);
    chunksum_kernel<<<nchunks, 256, 0, stream>>>(deg, chunkSum, n);
    scanchunks_kernel<<<1, 128, 0, stream>>>(chunkSum, nchunks);
    scanwithin_kernel<<<nchunks, 256, 0, stream>>>(deg, chunkSum, rowptr, n);
    fill_kernel<<<egrid, 256, 0, stream>>>(src, dst, rowptr, eidx, e);

    // ---- conv1 ----
    // h1 = x @ w1_lin.T + b            : ws0   (64 out -> 4 groups of 16)
    mv_kernel<FIN, HD, 16, false, false><<<dim3(ngrid, HD / 16), 256, 0, stream>>>(
        x, w1_lin, b1_lin, ws0, n);
    // agg1 = h1 + scatter              : ws1
    gather_kernel<HD><<<ggrid, 256, 0, stream>>>(rowptr, deg, eidx, ws0, ws1, n);
    // u1 = relu(o1 @ relu(agg1) + b)   : ws0
    mv_kernel<HD, HD, 16, true, true><<<dim3(ngrid, HD / 16), 256, 0, stream>>>(
        ws1, w1_o1, b1_o1, ws0, n);
    // hmid = relu(o2 @ u1 + b)         : ws1
    mv_kernel<HD, HD, 16, false, true><<<dim3(ngrid, HD / 16), 256, 0, stream>>>(
        ws0, w1_o2, b1_o2, ws1, n);

    // ---- conv2 ----
    // h2 = hmid @ w2_lin.T + b         : ws0   (40 out -> 5 groups of 8)
    mv_kernel<HD, CD, 8, false, false><<<dim3(ngrid, CD / 8), 256, 0, stream>>>(
        ws1, w2_lin, b2_lin, ws0, n);
    // agg2 = h2 + scatter              : ws1
    gather_kernel<CD><<<ggrid, 256, 0, stream>>>(rowptr, deg, eidx, ws0, ws1, n);
    // u2 = relu(o1 @ relu(agg2) + b)   : ws0
    mv_kernel<CD, CD, 8, true, true><<<dim3(ngrid, CD / 8), 256, 0, stream>>>(
        ws1, w2_o1, b2_o1, ws0, n);
    // out = o2 @ u2 + b                : d_out
    mv_kernel<CD, CD, 8, false, false><<<dim3(ngrid, CD / 8), 256, 0, stream>>>(
        ws0, w2_o2, b2_o2, outp, n);
}

// Round 7
// 623.319 us; speedup vs baseline: 1.7563x; 1.7563x over previous
//
#include <hip/hip_runtime.h>

static constexpr int FIN = 128;
static constexpr int HD  = 64;
static constexpr int CD  = 40;

// ---------------------------------------------------------------------------
// Transposed matvec: one WAVE (block=64) per node-chunk; lane = output chan.
//  - W row W[o,:] held in VGPRs (static unroll), loaded once per wave
//  - input row address is wave-uniform (readfirstlane) -> s_load scalar path
//  - out[node*O+lane] store fully coalesced
// R5 lesson: one-thread-per-node = scalar-latency-bound at 30% VALU.
// R6 lesson: o-splitting multiplies FETCH x15 (per-XCD L2 copies). This keeps
// single-pass input traffic AND high wave count (4000 waves).
// ---------------------------------------------------------------------------
template<int K, int O, bool IN_RELU, bool OUT_RELU>
__global__ __launch_bounds__(64)
void mvT_kernel(const float* __restrict__ in, const float* __restrict__ W,
                const float* __restrict__ bias, float* __restrict__ out,
                int n, int npw)
{
    const int lane = threadIdx.x;          // block = 1 wave of 64
    const int n0 = blockIdx.x * npw;
    if (n0 >= n) return;
    const int n1 = (n0 + npw < n) ? n0 + npw : n;
    const bool act = (lane < O);
    const int o = act ? lane : 0;

    // per-lane weight row -> registers (static indexing only)
    float w[K];
    const float* Wr = W + (size_t)o * K;
#pragma unroll
    for (int k = 0; k < K; k += 4) {
        float4 wv = *reinterpret_cast<const float4*>(Wr + k);
        w[k] = wv.x; w[k+1] = wv.y; w[k+2] = wv.z; w[k+3] = wv.w;
    }
    const float b = bias[o];

#pragma unroll 1
    for (int node = n0; node < n1; ++node) {
        const int nodeu = __builtin_amdgcn_readfirstlane(node);  // force uniform
        const float* row = in + (size_t)nodeu * K;
        float acc = b;
#pragma unroll
        for (int k = 0; k < K; k += 4) {
            float4 v = *reinterpret_cast<const float4*>(row + k);  // uniform -> s_load
            if (IN_RELU) {
                v.x = fmaxf(v.x, 0.f); v.y = fmaxf(v.y, 0.f);
                v.z = fmaxf(v.z, 0.f); v.w = fmaxf(v.w, 0.f);
            }
            acc = fmaf(v.x, w[k],     acc);
            acc = fmaf(v.y, w[k + 1], acc);
            acc = fmaf(v.z, w[k + 2], acc);
            acc = fmaf(v.w, w[k + 3], acc);
        }
        if (OUT_RELU) acc = fmaxf(acc, 0.f);
        if (act) out[(size_t)nodeu * O + lane] = acc;
    }
}

// ---------------------------------------------------------------------------
// CSR build.
// ---------------------------------------------------------------------------
__global__ __launch_bounds__(256)
void hist_kernel(const int* __restrict__ dst, int* __restrict__ deg, int e)
{
    int i = blockIdx.x * 256 + threadIdx.x;
    if (i < e) atomicAdd(&deg[dst[i]], 1);
}

__global__ __launch_bounds__(256)
void chunksum_kernel(const int* __restrict__ deg, int* __restrict__ chunkSum, int n)
{
    __shared__ int s[256];
    int t = threadIdx.x;
    int base = blockIdx.x * 1024 + t * 4;
    int v = 0;
#pragma unroll
    for (int i = 0; i < 4; ++i) if (base + i < n) v += deg[base + i];
    s[t] = v; __syncthreads();
    for (int off = 128; off > 0; off >>= 1) {
        if (t < off) s[t] += s[t + off];
        __syncthreads();
    }
    if (t == 0) chunkSum[blockIdx.x] = s[0];
}

__global__ __launch_bounds__(128)
void scanchunks_kernel(int* __restrict__ chunkSum, int nchunks)
{
    __shared__ int s[128];
    int t = threadIdx.x;
    int v = (t < nchunks) ? chunkSum[t] : 0;
    s[t] = v; __syncthreads();
    for (int off = 1; off < 128; off <<= 1) {
        int a = (t >= off) ? s[t - off] : 0;
        __syncthreads();
        s[t] += a;
        __syncthreads();
    }
    if (t < nchunks) chunkSum[t] = s[t] - v;   // exclusive
}

__global__ __launch_bounds__(256)
void scanwithin_kernel(const int* __restrict__ deg, const int* __restrict__ chunkOff,
                       int* __restrict__ rowptr, int n)
{
    __shared__ int s[256];
    int t = threadIdx.x;
    int base = blockIdx.x * 1024 + t * 4;
    int v[4]; int sum = 0;
#pragma unroll
    for (int i = 0; i < 4; ++i) { v[i] = (base + i < n) ? deg[base + i] : 0; sum += v[i]; }
    s[t] = sum; __syncthreads();
    for (int off = 1; off < 256; off <<= 1) {
        int a = (t >= off) ? s[t - off] : 0;
        __syncthreads();
        s[t] += a;
        __syncthreads();
    }
    int p = s[t] - sum + chunkOff[blockIdx.x];
#pragma unroll
    for (int i = 0; i < 4; ++i) {
        if (base + i < n) rowptr[base + i] = p;
        p += v[i];
    }
}

__global__ __launch_bounds__(256)
void fill_kernel(const int* __restrict__ src, const int* __restrict__ dst,
                 int* __restrict__ rowptr, int* __restrict__ eidx, int e)
{
    int i = blockIdx.x * 256 + threadIdx.x;
    if (i >= e) return;
    int pos = atomicAdd(&rowptr[dst[i]], 1);
    eidx[pos] = src[i];
}

// ---------------------------------------------------------------------------
// Gather: agg[d][c] = h[d][c] + sum_{e: dst=d} h[src_e][c].
// One wave per node, lane = channel.
// ---------------------------------------------------------------------------
template<int D>
__global__ __launch_bounds__(256)
void gather_kernel(const int* __restrict__ rowptr_end, const int* __restrict__ deg,
                   const int* __restrict__ eidx, const float* __restrict__ h,
                   float* __restrict__ agg, int n)
{
    int wave = threadIdx.x >> 6;
    int lane = threadIdx.x & 63;
    int node = blockIdx.x * 4 + wave;
    if (node >= n) return;
    bool act = (lane < D);
    float acc = act ? h[(size_t)node * D + lane] : 0.f;
    int end = rowptr_end[node];
    int start = end - deg[node];
    for (int base = start; base < end; base += 64) {
        int m = min(64, end - base);
        int sv = (lane < m) ? eidx[base + lane] : 0;
        for (int j = 0; j < m; ++j) {
            int s = __shfl(sv, j, 64);
            if (act) acc += h[(size_t)s * D + lane];
        }
    }
    if (act) agg[(size_t)node * D + lane] = acc;
}

extern "C" void kernel_launch(void* const* d_in, const int* in_sizes, int n_in,
                              void* d_out, int out_size, void* d_ws, size_t ws_size,
                              hipStream_t stream)
{
    const float* x      = (const float*)d_in[0];
    const int*   ei     = (const int*)d_in[1];
    const float* w1_lin = (const float*)d_in[2];
    const float* b1_lin = (const float*)d_in[3];
    const float* w1_o1  = (const float*)d_in[4];
    const float* b1_o1  = (const float*)d_in[5];
    const float* w1_o2  = (const float*)d_in[6];
    const float* b1_o2  = (const float*)d_in[7];
    const float* w2_lin = (const float*)d_in[8];
    const float* b2_lin = (const float*)d_in[9];
    const float* w2_o1  = (const float*)d_in[10];
    const float* b2_o1  = (const float*)d_in[11];
    const float* w2_o2  = (const float*)d_in[12];
    const float* b2_o2  = (const float*)d_in[13];

    const int n = in_sizes[0] / FIN;   // 100000
    const int e = in_sizes[1] / 2;     // 1000000
    const int* src = ei;
    const int* dst = ei + e;

    // Two float buffers in d_ws, strict ping-pong:
    float* ws0 = (float*)d_ws;
    float* ws1 = ws0 + (size_t)n * HD;
    float* outp = (float*)d_out;

    // CSR arrays live in d_out (16 MB; last consumer is gather40, before the
    // final mv writes d_out).
    int* eidx     = (int*)d_out;
    int* deg      = eidx + e;
    int* rowptr   = deg + n;
    int* chunkSum = rowptr + n;

    const int nchunks = (n + 1023) / 1024;        // 98 (<=128)
    const int egrid   = (e + 255) / 256;
    const int ggrid   = (n + 3) / 4;

    // dense grid: 1 wave per block, ~4000 waves, 25 nodes per wave
    const int npw   = 25;
    const int mgrid = (n + npw - 1) / npw;

    // ---- CSR build (reused by both layers) ----
    hipMemsetAsync(deg, 0, (size_t)n * sizeof(int), stream);
    hist_kernel<<<egrid, 256, 0, stream>>>(dst, deg, e);
    chunksum_kernel<<<nchunks, 256, 0, stream>>>(deg, chunkSum, n);
    scanchunks_kernel<<<1, 128, 0, stream>>>(chunkSum, nchunks);
    scanwithin_kernel<<<nchunks, 256, 0, stream>>>(deg, chunkSum, rowptr, n);
    fill_kernel<<<egrid, 256, 0, stream>>>(src, dst, rowptr, eidx, e);

    // ---- conv1 ----
    // h1 = x @ w1_lin.T + b            : ws0
    mvT_kernel<FIN, HD, false, false><<<mgrid, 64, 0, stream>>>(x, w1_lin, b1_lin, ws0, n, npw);
    // agg1 = h1 + scatter              : ws1
    gather_kernel<HD><<<ggrid, 256, 0, stream>>>(rowptr, deg, eidx, ws0, ws1, n);
    // u1 = relu(o1 @ relu(agg1) + b)   : ws0
    mvT_kernel<HD, HD, true, true><<<mgrid, 64, 0, stream>>>(ws1, w1_o1, b1_o1, ws0, n, npw);
    // hmid = relu(o2 @ u1 + b)         : ws1
    mvT_kernel<HD, HD, false, true><<<mgrid, 64, 0, stream>>>(ws0, w1_o2, b1_o2, ws1, n, npw);

    // ---- conv2 ----
    // h2 = hmid @ w2_lin.T + b         : ws0
    mvT_kernel<HD, CD, false, false><<<mgrid, 64, 0, stream>>>(ws1, w2_lin, b2_lin, ws0, n, npw);
    // agg2 = h2 + scatter              : ws1
    gather_kernel<CD><<<ggrid, 256, 0, stream>>>(rowptr, deg, eidx, ws0, ws1, n);
    // u2 = relu(o1 @ relu(agg2) + b)   : ws0
    mvT_kernel<CD, CD, true, true><<<mgrid, 64, 0, stream>>>(ws1, w2_o1, b2_o1, ws0, n, npw);
    // out = o2 @ u2 + b                : d_out
    mvT_kernel<CD, CD, false, false><<<mgrid, 64, 0, stream>>>(ws0, w2_o2, b2_o2, outp, n, npw);
}